// Round 3
// baseline (569.852 us; speedup 1.0000x reference)
//
#include <hip/hip_runtime.h>
#include <hip/hip_bf16.h>
#include <math.h>

#define NHEADS 4
#define NM 32          // N_MODES (F == G == 32)
#define CIN 32
#define COUT 32
#define SPD 3
#define BATCH 2
#define NPTS (48*48*48)          // 110592 per batch
#define CHUNK 64
#define PTS_PER_BLOCK 256        // 4 chunks of 64
#define SEGS (NPTS / PTS_PER_BLOCK)   // 432
#define INV_N (1.0f / (float)NPTS)

// load one 32-float row (128 B, aligned) into registers
__device__ __forceinline__ void load_row32(const float* __restrict__ p, float* r) {
    const float4* q4 = (const float4*)p;
#pragma unroll
    for (int v = 0; v < 8; ++v) {
        float4 f = q4[v];
        r[4*v+0] = f.x; r[4*v+1] = f.y; r[4*v+2] = f.z; r[4*v+3] = f.w;
    }
}

// ---------------------------------------------------------------------------
// Kernel 1: AX[b,h,f,g] (complex) = sum_n A[b,h,n,f] * X[b,h,n,g]
//   A = a . a_modes  (real);  X = exp(-2*pi*i * (x . x_modes))
// ws layout: AXre [B][H][32][32] floats, then AXim (8192 + 8192 floats).
// ---------------------------------------------------------------------------
__global__ __launch_bounds__(256, 2) void k_ax(
    const float* __restrict__ a, const float* __restrict__ x,
    const float* __restrict__ a_modes, const float* __restrict__ x_modes,
    float* __restrict__ AX)
{
    __shared__ __align__(16) float s_am[NHEADS][NM][CIN];  // broadcast float4 reads
    __shared__ __align__(16) float s_xm[NHEADS][NM][SPD];
    __shared__ __align__(16) float s_A[CHUNK][NM + 1];     // +1 pad: per-lane access
    __shared__ __align__(16) float s_Xre[CHUNK][NM];       // unpadded: float4 reads
    __shared__ __align__(16) float s_Xim[CHUNK][NM];
    __shared__ __align__(16) float s_xT[SPD][CHUNK];

    const int t   = threadIdx.x;
    const int b   = blockIdx.x / SEGS;
    const int seg = blockIdx.x % SEGS;
    const int pt0 = seg * PTS_PER_BLOCK;

    for (int idx = t; idx < NHEADS*NM*CIN; idx += 256)
        ((float*)s_am)[idx] = a_modes[idx];
    for (int idx = t; idx < NHEADS*NM*SPD; idx += 256)
        ((float*)s_xm)[idx] = x_modes[idx];

    float accre[NHEADS][4], accim[NHEADS][4];
#pragma unroll
    for (int h = 0; h < NHEADS; ++h)
#pragma unroll
        for (int j = 0; j < 4; ++j) { accre[h][j] = 0.f; accim[h][j] = 0.f; }

    const int klane = t & 63;     // point within chunk (a-row owner)
    const int kq    = t >> 6;     // 0..3
    const int fa    = t >> 3;     // accumulator f (0..31)
    const int g0    = (t & 7) * 4;

    for (int c = 0; c < PTS_PER_BLOCK / CHUNK; ++c) {
        const int base = b * NPTS + pt0 + c * CHUNK;
        __syncthreads();
        if (t < CHUNK * SPD) {
            int k = t / 3, d = t - 3 * k;
            s_xT[d][k] = x[(size_t)base * SPD + t];
        }
        float areg[32];
        load_row32(a + (size_t)(base + klane) * CIN, areg);
        __syncthreads();

        for (int h = 0; h < NHEADS; ++h) {
            // A[k][j] for j = kq + 4e  (a_modes row wave-uniform -> broadcast)
#pragma unroll
            for (int e = 0; e < 8; ++e) {
                const int j = kq + 4 * e;
                float s = 0.f;
#pragma unroll
                for (int i = 0; i < 32; i += 4) {
                    const float4 m = *(const float4*)&s_am[h][j][i];
                    s += areg[i]*m.x + areg[i+1]*m.y + areg[i+2]*m.z + areg[i+3]*m.w;
                }
                s_A[klane][j] = s;
            }
            // X[k2][g]: phase already in revolutions -> raw v_sin/v_cos
#pragma unroll
            for (int e = 0; e < 8; ++e) {
                const int v = t + 256 * e;
                const int k2 = v >> 5, g = v & 31;
                const float px = s_xT[0][k2]*s_xm[h][g][0]
                               + s_xT[1][k2]*s_xm[h][g][1]
                               + s_xT[2][k2]*s_xm[h][g][2];
                s_Xre[k2][g] =  __builtin_amdgcn_cosf(px);
                s_Xim[k2][g] = -__builtin_amdgcn_sinf(px);
            }
            __syncthreads();
            // rank-1 accumulate: acc[f][g0..g0+3] += A[k][f] * X[k][g]
#pragma unroll 4
            for (int k = 0; k < CHUNK; ++k) {
                const float av = s_A[k][fa];
                const float4 xr = *(const float4*)&s_Xre[k][g0];
                const float4 xi = *(const float4*)&s_Xim[k][g0];
                accre[h][0] += av * xr.x; accre[h][1] += av * xr.y;
                accre[h][2] += av * xr.z; accre[h][3] += av * xr.w;
                accim[h][0] += av * xi.x; accim[h][1] += av * xi.y;
                accim[h][2] += av * xi.z; accim[h][3] += av * xi.w;
            }
            __syncthreads();
        }
    }

    float* AXre = AX;
    float* AXim = AX + BATCH * NHEADS * NM * NM;
#pragma unroll
    for (int h = 0; h < NHEADS; ++h)
#pragma unroll
        for (int j = 0; j < 4; ++j) {
            const int idx = ((b * NHEADS + h) * NM + fa) * NM + g0 + j;
            atomicAdd(&AXre[idx], accre[h][j]);
            atomicAdd(&AXim[idx], accim[h][j]);
        }
}

// ---------------------------------------------------------------------------
// Kernel 2: U = Re(AX * Y)/N ; out = gelu(U . u_modes + a . fc_w^T + fc_b)
// ---------------------------------------------------------------------------
__global__ __launch_bounds__(256, 2) void k_out(
    const float* __restrict__ a, const float* __restrict__ y,
    const float* __restrict__ y_modes, const float* __restrict__ u_modes,
    const float* __restrict__ fc_w, const float* __restrict__ fc_b,
    const float* __restrict__ AX, float* __restrict__ out)
{
    __shared__ __align__(16) float s_re[NHEADS][NM][NM];   // broadcast float4 reads
    __shared__ __align__(16) float s_im[NHEADS][NM][NM];
    __shared__ __align__(16) float s_um[NHEADS][NM][COUT];
    __shared__ __align__(16) float s_fw[COUT][CIN];
    __shared__ __align__(16) float s_fb[COUT];
    __shared__ __align__(16) float s_ym[NHEADS][NM][SPD];
    __shared__ __align__(16) float s_yT[SPD][CHUNK];
    __shared__ __align__(16) float s_Yre[CHUNK][NM + 1];
    __shared__ __align__(16) float s_Yim[CHUNK][NM + 1];
    __shared__ __align__(16) float s_U[CHUNK][NM + 1];

    const int t   = threadIdx.x;
    const int b   = blockIdx.x / SEGS;
    const int seg = blockIdx.x % SEGS;
    const int pt0 = seg * PTS_PER_BLOCK;

    const float* AXre = AX;
    const float* AXim = AX + BATCH * NHEADS * NM * NM;
    for (int idx = t; idx < NHEADS*NM*NM; idx += 256) {
        ((float*)s_re)[idx] = AXre[b * NHEADS*NM*NM + idx] * INV_N;
        ((float*)s_im)[idx] = AXim[b * NHEADS*NM*NM + idx] * INV_N;
        ((float*)s_um)[idx] = u_modes[idx];
    }
    for (int idx = t; idx < COUT*CIN; idx += 256)
        ((float*)s_fw)[idx] = fc_w[idx];
    if (t < COUT) s_fb[t] = fc_b[t];
    for (int idx = t; idx < NHEADS*NM*SPD; idx += 256)
        ((float*)s_ym)[idx] = y_modes[idx];

    const int klane = t & 63;
    const int q     = t >> 6;      // 0..3
    const int o0    = q * 8;

    for (int c = 0; c < PTS_PER_BLOCK / CHUNK; ++c) {
        const int base = b * NPTS + pt0 + c * CHUNK;
        __syncthreads();
        if (t < CHUNK * SPD) {
            int k = t / 3, d = t - 3 * k;
            s_yT[d][k] = y[(size_t)base * SPD + t];
        }
        // fused skip: acc[j] = fc_b[o] + a-row . fc_w[o]
        float acc[8];
        {
            float areg[32];
            load_row32(a + (size_t)(base + klane) * CIN, areg);
#pragma unroll
            for (int j = 0; j < 8; ++j) {
                const int o = o0 + j;
                float s = s_fb[o];
#pragma unroll
                for (int i = 0; i < 32; i += 4) {
                    const float4 w = *(const float4*)&s_fw[o][i];
                    s += areg[i]*w.x + areg[i+1]*w.y + areg[i+2]*w.z + areg[i+3]*w.w;
                }
                acc[j] = s;
            }
        }
        __syncthreads();

        for (int h = 0; h < NHEADS; ++h) {
            // Y[k2][g] = exp(+2*pi*i*py)
#pragma unroll
            for (int e = 0; e < 8; ++e) {
                const int v = t + 256 * e;
                const int k2 = v >> 5, g = v & 31;
                const float py = s_yT[0][k2]*s_ym[h][g][0]
                               + s_yT[1][k2]*s_ym[h][g][1]
                               + s_yT[2][k2]*s_ym[h][g][2];
                s_Yre[k2][g] = __builtin_amdgcn_cosf(py);
                s_Yim[k2][g] = __builtin_amdgcn_sinf(py);
            }
            __syncthreads();
            float yre[32], yim[32];
#pragma unroll
            for (int g = 0; g < 32; ++g) {
                yre[g] = s_Yre[klane][g];
                yim[g] = s_Yim[klane][g];
            }
            // U[k][f] for f = q + 4e
#pragma unroll
            for (int e = 0; e < 8; ++e) {
                const int f = q + 4 * e;
                float u = 0.f;
#pragma unroll
                for (int g = 0; g < 32; g += 4) {
                    const float4 r4 = *(const float4*)&s_re[h][f][g];
                    const float4 i4 = *(const float4*)&s_im[h][f][g];
                    u += r4.x*yre[g] + r4.y*yre[g+1] + r4.z*yre[g+2] + r4.w*yre[g+3];
                    u -= i4.x*yim[g] + i4.y*yim[g+1] + i4.z*yim[g+2] + i4.w*yim[g+3];
                }
                s_U[klane][f] = u;
            }
            __syncthreads();
            // att: acc[o] += sum_f U[k][f] * u_modes[h][f][o]
#pragma unroll 4
            for (int f = 0; f < 32; ++f) {
                const float u = s_U[klane][f];
                const float4 m0 = *(const float4*)&s_um[h][f][o0];
                const float4 m1 = *(const float4*)&s_um[h][f][o0 + 4];
                acc[0] += u*m0.x; acc[1] += u*m0.y; acc[2] += u*m0.z; acc[3] += u*m0.w;
                acc[4] += u*m1.x; acc[5] += u*m1.y; acc[6] += u*m1.z; acc[7] += u*m1.w;
            }
        }

        // exact GELU + f32 store (2 x float4 per lane)
        float4 r0, r1;
        {
            float g0v = acc[0], g1v = acc[1], g2v = acc[2], g3v = acc[3];
            float g4v = acc[4], g5v = acc[5], g6v = acc[6], g7v = acc[7];
            r0.x = 0.5f*g0v*(1.0f + erff(g0v*0.70710678118654752f));
            r0.y = 0.5f*g1v*(1.0f + erff(g1v*0.70710678118654752f));
            r0.z = 0.5f*g2v*(1.0f + erff(g2v*0.70710678118654752f));
            r0.w = 0.5f*g3v*(1.0f + erff(g3v*0.70710678118654752f));
            r1.x = 0.5f*g4v*(1.0f + erff(g4v*0.70710678118654752f));
            r1.y = 0.5f*g5v*(1.0f + erff(g5v*0.70710678118654752f));
            r1.z = 0.5f*g6v*(1.0f + erff(g6v*0.70710678118654752f));
            r1.w = 0.5f*g7v*(1.0f + erff(g7v*0.70710678118654752f));
        }
        float* po = out + (size_t)(base + klane) * COUT + o0;
        *(float4*)po = r0;
        *(float4*)(po + 4) = r1;
    }
}

extern "C" void kernel_launch(void* const* d_in, const int* in_sizes, int n_in,
                              void* d_out, int out_size, void* d_ws, size_t ws_size,
                              hipStream_t stream) {
    (void)in_sizes; (void)n_in; (void)out_size; (void)ws_size;
    const float* a       = (const float*)d_in[0];
    const float* x       = (const float*)d_in[1];
    const float* y       = (const float*)d_in[2];
    const float* a_modes = (const float*)d_in[3];
    const float* x_modes = (const float*)d_in[4];
    const float* y_modes = (const float*)d_in[5];
    const float* u_modes = (const float*)d_in[6];
    const float* fc_w    = (const float*)d_in[7];
    const float* fc_b    = (const float*)d_in[8];
    float* out = (float*)d_out;
    float* AX = (float*)d_ws;   // 2 * B*H*32*32 floats = 64 KB

    hipMemsetAsync(AX, 0, (size_t)2 * BATCH * NHEADS * NM * NM * sizeof(float), stream);
    k_ax<<<BATCH * SEGS, 256, 0, stream>>>(a, x, a_modes, x_modes, AX);
    k_out<<<BATCH * SEGS, 256, 0, stream>>>(a, y, y_modes, u_modes, fc_w, fc_b, AX, out);
}

// Round 4
// 169.640 us; speedup vs baseline: 3.3592x; 3.3592x over previous
//
#include <hip/hip_runtime.h>
#include <hip/hip_bf16.h>
#include <math.h>

#define NHEADS 4
#define NM 32
#define CIN 32
#define COUT 32
#define BATCH 2
#define NPTS (48*48*48)           // 110592 per batch
#define PAD 36                    // padded LDS row (bf16 elems): 72 B, 8B-aligned, 2-way banks
#define SEGS_AX (NPTS/256)        // 432
#define SEGS_OUT (NPTS/128)       // 864
#define INV_N (1.0f / (float)NPTS)

typedef unsigned short ushort_t;
typedef __attribute__((ext_vector_type(8))) short short8;     // 8 x bf16 MFMA frag
typedef __attribute__((ext_vector_type(16))) float floatx16;  // 32x32 C/D frag

#define MFMA32 __builtin_amdgcn_mfma_f32_32x32x16_bf16

union frag8 { short8 v; uint2 u2[2]; unsigned u[4]; ushort_t s[8]; };

__device__ __forceinline__ floatx16 zero16() {
    floatx16 z;
#pragma unroll
    for (int i = 0; i < 16; ++i) z[i] = 0.0f;
    return z;
}
__device__ __forceinline__ ushort_t f2bf(float f) {
    __hip_bfloat16 h = __float2bfloat16(f);
    return *(ushort_t*)&h;
}
__device__ __forceinline__ float bf2f(ushort_t u) {
    union { unsigned i; float f; } v; v.i = ((unsigned)u) << 16; return v.f;
}
__device__ __forceinline__ unsigned pk2(float a, float b) {
    return (unsigned)f2bf(a) | ((unsigned)f2bf(b) << 16);
}
// build frag from 8 consecutive f32 (16B-aligned global/generic ptr), scaled
__device__ __forceinline__ short8 frag_from_f32(const float* __restrict__ p, float scale) {
    float4 f0 = ((const float4*)p)[0], f1 = ((const float4*)p)[1];
    frag8 r;
    r.u[0] = pk2(f0.x * scale, f0.y * scale);
    r.u[1] = pk2(f0.z * scale, f0.w * scale);
    r.u[2] = pk2(f1.x * scale, f1.y * scale);
    r.u[3] = pk2(f1.z * scale, f1.w * scale);
    return r.v;
}
// read 8 consecutive bf16 (16 B, 8B-aligned) from LDS
__device__ __forceinline__ short8 frag_lds(const ushort_t* p) {
    frag8 r;
    r.u2[0] = *(const uint2*)p;
    r.u2[1] = *(const uint2*)(p + 4);
    return r.v;
}

// ---------------------------------------------------------------------------
// k_ax: AX[b,h,f,g] = sum_n A[n,f] * X[n,g];  A = a . a_modes (MFMA),
// X = exp(-2pi*i x.x_modes). Wave = head. Per-wave private LDS tiles ->
// one __syncthreads total. Output: per-block partials (or atomic fallback).
// ---------------------------------------------------------------------------
__global__ __launch_bounds__(256, 3) void k_ax(
    const float* __restrict__ a, const float* __restrict__ x,
    const float* __restrict__ a_modes, const float* __restrict__ x_modes,
    float* __restrict__ AX, float* __restrict__ part, int use_part)
{
    __shared__ ushort_t s_a[256][PAD];          // a tile bf16 [pt][i]
    __shared__ float    s_xT[3][256];
    __shared__ ushort_t s_At[NHEADS][NM][PAD];  // A^T bf16 [f][pt] (per wave)
    __shared__ ushort_t s_Xre[NHEADS][NM][PAD]; // X^T bf16 [g][pt] (per wave)
    __shared__ ushort_t s_Xim[NHEADS][NM][PAD];

    const int t = threadIdx.x;
    const int w = t >> 6;              // wave id == head
    const int l = t & 63;
    const int l31 = l & 31, lh = l >> 5;
    const int b  = blockIdx.x / SEGS_AX;
    const int sb = blockIdx.x % SEGS_AX;
    const int pbase = b * NPTS + sb * 256;

    // stage a (bf16, one row per thread) and x (f32)
    {
        const float* arow = a + (size_t)(pbase + t) * CIN;
        unsigned* dst = (unsigned*)&s_a[t][0];
#pragma unroll
        for (int v = 0; v < 8; ++v) {
            float4 f = ((const float4*)arow)[v];
            dst[2*v]   = pk2(f.x, f.y);
            dst[2*v+1] = pk2(f.z, f.w);
        }
        for (int idx = t; idx < 256*3; idx += 256)
            s_xT[idx % 3][idx / 3] = x[(size_t)pbase * 3 + idx];
    }
    // a_modes frags in regs: A-op [m=f=l31][k=i], i-chunk = kh*16 + lh*8
    short8 amf[2];
#pragma unroll
    for (int kh = 0; kh < 2; ++kh)
        amf[kh] = frag_from_f32(a_modes + (w*NM + l31)*CIN + kh*16 + lh*8, 1.0f);
    // x_modes row for this lane's g = l31 (fixed)
    const float xm0 = x_modes[(w*NM + l31)*3 + 0];
    const float xm1 = x_modes[(w*NM + l31)*3 + 1];
    const float xm2 = x_modes[(w*NM + l31)*3 + 2];

    floatx16 accre = zero16(), accim = zero16();
    __syncthreads();   // the only block barrier

    for (int c = 0; c < 8; ++c) {
        const int p0 = c * 32;
        // ---- A tile: D[f][pt] = sum_i am[f][i] * a[pt][i] ----
        floatx16 dA = zero16();
#pragma unroll
        for (int kh = 0; kh < 2; ++kh) {
            short8 af = frag_lds(&s_a[p0 + l31][kh*16 + lh*8]);  // B-op [n=pt][k=i]
            dA = MFMA32(amf[kh], af, dA, 0, 0, 0);
        }
        // C-layout (col=pt=l31, row=f over regs) -> bf16 [f][pt] in private LDS
#pragma unroll
        for (int r = 0; r < 16; ++r) {
            const int fr = (r & 3) + 8*(r >> 2) + 4*lh;
            s_At[w][fr][l31] = f2bf(dA[r]);
        }
        // ---- X tile: lane (g=l31, pt=lh*16+j), phases in revolutions ----
#pragma unroll
        for (int j = 0; j < 16; j += 2) {
            const int pl = lh*16 + j;
            const int pt = p0 + pl;
            const float px0 = s_xT[0][pt]*xm0 + s_xT[1][pt]*xm1 + s_xT[2][pt]*xm2;
            const float px1 = s_xT[0][pt+1]*xm0 + s_xT[1][pt+1]*xm1 + s_xT[2][pt+1]*xm2;
            *(unsigned*)&s_Xre[w][l31][pl] =
                pk2(__builtin_amdgcn_cosf(px0), __builtin_amdgcn_cosf(px1));
            *(unsigned*)&s_Xim[w][l31][pl] =
                pk2(-__builtin_amdgcn_sinf(px0), -__builtin_amdgcn_sinf(px1));
        }
        // ---- AX accumulate: D[f][g] += sum_pt At[f][pt] * X^T[g][pt] ----
        // (same-wave LDS ops are processed in order -> no barrier needed)
#pragma unroll
        for (int kh = 0; kh < 2; ++kh) {
            short8 atf = frag_lds(&s_At[w][l31][kh*16 + lh*8]);   // A-op [f][pt]
            short8 xrf = frag_lds(&s_Xre[w][l31][kh*16 + lh*8]);  // B-op [g][pt]
            short8 xif = frag_lds(&s_Xim[w][l31][kh*16 + lh*8]);
            accre = MFMA32(atf, xrf, accre, 0, 0, 0);
            accim = MFMA32(atf, xif, accim, 0, 0, 0);
        }
    }

    // epilogue: col g = l31, row f per reg
    if (use_part) {
        float* pr = part + (size_t)blockIdx.x * 8192;
#pragma unroll
        for (int r = 0; r < 16; ++r) {
            const int fr = (r & 3) + 8*(r >> 2) + 4*lh;
            const int idx = (w*NM + fr)*NM + l31;
            pr[idx]        = accre[r];
            pr[idx + 4096] = accim[r];
        }
    } else {
        float* AXre = AX;
        float* AXim = AX + BATCH*NHEADS*NM*NM;
#pragma unroll
        for (int r = 0; r < 16; ++r) {
            const int fr = (r & 3) + 8*(r >> 2) + 4*lh;
            const int idx = b*4096 + (w*NM + fr)*NM + l31;
            atomicAdd(&AXre[idx], accre[r]);
            atomicAdd(&AXim[idx], accim[r]);
        }
    }
}

// ---------------------------------------------------------------------------
// k_red: AX[o] = sum over 432 per-block partials (coalesced, 4-way split)
// ---------------------------------------------------------------------------
__global__ void k_red(const float* __restrict__ part, float* __restrict__ AX)
{
    __shared__ float s_red[4][64];
    const int t = threadIdx.x, q = t >> 6, l = t & 63;
    const int o = blockIdx.x * 64 + l;        // 0..16383
    const int bb = o >> 13;
    const int idx = o & 8191;
    float acc = 0.f;
#pragma unroll 4
    for (int sb = q; sb < SEGS_AX; sb += 4)
        acc += part[((size_t)(bb*SEGS_AX + sb))*8192 + idx];
    s_red[q][l] = acc;
    __syncthreads();
    if (q == 0) {
        const float s = s_red[0][l] + s_red[1][l] + s_red[2][l] + s_red[3][l];
        if (idx < 4096) AX[bb*4096 + idx] = s;
        else            AX[8192 + bb*4096 + (idx - 4096)] = s;
    }
}

// ---------------------------------------------------------------------------
// k_out: U = Re(AX'*Y); out = gelu(U.u_modes + a.fc_w^T + fc_b)
// Wave = 32 points; head loop accumulates att+skip in MFMA C regs.
// ---------------------------------------------------------------------------
__global__ __launch_bounds__(256, 3) void k_out(
    const float* __restrict__ a, const float* __restrict__ y,
    const float* __restrict__ y_modes, const float* __restrict__ u_modes,
    const float* __restrict__ fc_w, const float* __restrict__ fc_b,
    const float* __restrict__ AX, float* __restrict__ out)
{
    __shared__ ushort_t s_umT[NHEADS][NM][PAD];  // [h][o][f] bf16
    __shared__ float    s_ym[NHEADS][NM][3];
    __shared__ float    s_yT[3][128];
    __shared__ ushort_t s_ah[128][PAD];          // a tile bf16 [pt][i]
    __shared__ ushort_t s_Yre[4][NM][PAD];       // per wave [pt][g]
    __shared__ ushort_t s_Yim[4][NM][PAD];       // holds MINUS sin
    __shared__ ushort_t s_U[4][NM][PAD];         // per wave [pt][f]

    const int t = threadIdx.x, w = t >> 6, l = t & 63;
    const int l31 = l & 31, lh = l >> 5;
    const int b  = blockIdx.x / SEGS_OUT;
    const int sb = blockIdx.x % SEGS_OUT;
    const int pblock = b * NPTS + sb * 128;
    const int pwave  = pblock + w * 32;

    // ---- stage (once) ----
    for (int idx = t; idx < NHEADS*NM*NM; idx += 256) {
        const int h = idx >> 10, f = (idx >> 5) & 31, o = idx & 31;
        s_umT[h][o][f] = f2bf(u_modes[idx]);
    }
    for (int idx = t; idx < NHEADS*NM*3; idx += 256)
        ((float*)s_ym)[idx] = y_modes[idx];
    for (int idx = t; idx < 128*3; idx += 256)
        s_yT[idx % 3][idx / 3] = y[(size_t)pblock * 3 + idx];
    if (t < 128) {
        const float* arow = a + (size_t)(pblock + t) * CIN;
        unsigned* dst = (unsigned*)&s_ah[t][0];
#pragma unroll
        for (int v = 0; v < 8; ++v) {
            float4 f = ((const float4*)arow)[v];
            dst[2*v]   = pk2(f.x, f.y);
            dst[2*v+1] = pk2(f.z, f.w);
        }
    }
    // ---- register frags ----
    short8 axre[NHEADS][2], axim[NHEADS][2];   // B-op [n=f=l31][k=g]
    {
        const float* AXre = AX;
        const float* AXim = AX + BATCH*NHEADS*NM*NM;
#pragma unroll
        for (int h = 0; h < NHEADS; ++h)
#pragma unroll
            for (int kh = 0; kh < 2; ++kh) {
                const int off = b*4096 + (h*NM + l31)*NM + kh*16 + lh*8;
                axre[h][kh] = frag_from_f32(AXre + off, INV_N);
                axim[h][kh] = frag_from_f32(AXim + off, INV_N);
            }
    }
    short8 whi[2], wlo[2];                     // B-op [n=o=l31][k=i], hi/lo split
#pragma unroll
    for (int kh = 0; kh < 2; ++kh) {
        const float* p = fc_w + l31*CIN + kh*16 + lh*8;
        float4 f0 = ((const float4*)p)[0], f1 = ((const float4*)p)[1];
        float v[8] = {f0.x,f0.y,f0.z,f0.w,f1.x,f1.y,f1.z,f1.w};
        frag8 hi, lo;
#pragma unroll
        for (int j = 0; j < 8; ++j) {
            const ushort_t hb = f2bf(v[j]);
            hi.s[j] = hb;
            lo.s[j] = f2bf(v[j] - bf2f(hb));
        }
        whi[kh] = hi.v; wlo[kh] = lo.v;
    }
    const float fb = fc_b[l31];

    __syncthreads();   // the only block barrier
    float y3[3];
#pragma unroll
    for (int d = 0; d < 3; ++d) y3[d] = s_yT[d][w*32 + l31];

    // ---- skip via MFMA: D[pt][o] = sum_i a[pt][i] * (whi+wlo)[o][i] ----
    floatx16 acc = zero16();
#pragma unroll
    for (int kh = 0; kh < 2; ++kh) {
        short8 af = frag_lds(&s_ah[w*32 + l31][kh*16 + lh*8]);  // A-op [m=pt][k=i]
        acc = MFMA32(af, whi[kh], acc, 0, 0, 0);
        acc = MFMA32(af, wlo[kh], acc, 0, 0, 0);
    }
    // ---- heads ----
    for (int h = 0; h < NHEADS; ++h) {
        // Y tile: lane (pt=l31 fixed, g=lh*16+j); Y=exp(+2pi*i py)
#pragma unroll
        for (int j = 0; j < 16; j += 2) {
            const int g0 = lh*16 + j;
            const float py0 = y3[0]*s_ym[h][g0][0]   + y3[1]*s_ym[h][g0][1]   + y3[2]*s_ym[h][g0][2];
            const float py1 = y3[0]*s_ym[h][g0+1][0] + y3[1]*s_ym[h][g0+1][1] + y3[2]*s_ym[h][g0+1][2];
            *(unsigned*)&s_Yre[w][l31][g0] =
                pk2(__builtin_amdgcn_cosf(py0), __builtin_amdgcn_cosf(py1));
            *(unsigned*)&s_Yim[w][l31][g0] =
                pk2(-__builtin_amdgcn_sinf(py0), -__builtin_amdgcn_sinf(py1));
        }
        // U[pt][f] = Yre.AXre' + (-Yim).AXim'   (in-order wave LDS, no barrier)
        floatx16 du = zero16();
#pragma unroll
        for (int kh = 0; kh < 2; ++kh) {
            short8 yr = frag_lds(&s_Yre[w][l31][kh*16 + lh*8]);  // A-op [m=pt][k=g]
            short8 yi = frag_lds(&s_Yim[w][l31][kh*16 + lh*8]);
            du = MFMA32(yr, axre[h][kh], du, 0, 0, 0);
            du = MFMA32(yi, axim[h][kh], du, 0, 0, 0);
        }
        // U (col=f=l31, rows pt) -> bf16 [pt][f]
#pragma unroll
        for (int r = 0; r < 16; ++r) {
            const int ptr_ = (r & 3) + 8*(r >> 2) + 4*lh;
            s_U[w][ptr_][l31] = f2bf(du[r]);
        }
        // att += U . umT : D[pt][o]
#pragma unroll
        for (int kh = 0; kh < 2; ++kh) {
            short8 uf = frag_lds(&s_U[w][l31][kh*16 + lh*8]);     // A-op [m=pt][k=f]
            short8 mf = frag_lds(&s_umT[h][l31][kh*16 + lh*8]);   // B-op [n=o][k=f]
            acc = MFMA32(uf, mf, acc, 0, 0, 0);
        }
    }
    // ---- epilogue: bias + exact GELU + store (col=o=l31, rows pt) ----
#pragma unroll
    for (int r = 0; r < 16; ++r) {
        const int ptr_ = (r & 3) + 8*(r >> 2) + 4*lh;
        const float z = acc[r] + fb;
        out[(size_t)(pwave + ptr_) * COUT + l31] =
            0.5f * z * (1.0f + erff(z * 0.70710678118654752f));
    }
}

extern "C" void kernel_launch(void* const* d_in, const int* in_sizes, int n_in,
                              void* d_out, int out_size, void* d_ws, size_t ws_size,
                              hipStream_t stream) {
    (void)in_sizes; (void)n_in; (void)out_size;
    const float* a       = (const float*)d_in[0];
    const float* x       = (const float*)d_in[1];
    const float* y       = (const float*)d_in[2];
    const float* a_modes = (const float*)d_in[3];
    const float* x_modes = (const float*)d_in[4];
    const float* y_modes = (const float*)d_in[5];
    const float* u_modes = (const float*)d_in[6];
    const float* fc_w    = (const float*)d_in[7];
    const float* fc_b    = (const float*)d_in[8];
    float* out  = (float*)d_out;
    float* AX   = (float*)d_ws;                        // 16384 f32 = 64 KB
    float* part = (float*)((char*)d_ws + 65536);       // 864*8192 f32 = 28.3 MB

    const size_t need = 65536 + (size_t)BATCH * SEGS_AX * 8192 * sizeof(float);
    const int use_part = (ws_size >= need) ? 1 : 0;

    hipMemsetAsync(AX, 0, 65536, stream);  // needed only for atomic fallback
    k_ax<<<BATCH * SEGS_AX, 256, 0, stream>>>(a, x, a_modes, x_modes, AX, part, use_part);
    if (use_part) k_red<<<256, 256, 0, stream>>>(part, AX);
    k_out<<<BATCH * SEGS_OUT, 256, 0, stream>>>(a, y, y_modes, u_modes, fc_w, fc_b, AX, out);
}

// Round 5
// 152.188 us; speedup vs baseline: 3.7444x; 1.1147x over previous
//
#include <hip/hip_runtime.h>
#include <hip/hip_bf16.h>
#include <math.h>

#define NHEADS 4
#define NM 32
#define CIN 32
#define COUT 32
#define BATCH 2
#define NPTS (48*48*48)           // 110592 per batch
#define PAD 36                    // padded LDS row (bf16): 72 B, 8B-aligned frags
#define SEGS_AX (NPTS/256)        // 432
#define SEGS_OUT (NPTS/128)       // 864
#define INV_N (1.0f / (float)NPTS)

typedef unsigned short ushort_t;
typedef __attribute__((ext_vector_type(8))) short short8;     // 8 x bf16 frag
typedef __attribute__((ext_vector_type(16))) float floatx16;  // 32x32 C/D frag

#define MFMA32 __builtin_amdgcn_mfma_f32_32x32x16_bf16

union frag8 { short8 v; uint2 u2[2]; unsigned u[4]; ushort_t s[8]; };

__device__ __forceinline__ floatx16 zero16() {
    floatx16 z;
#pragma unroll
    for (int i = 0; i < 16; ++i) z[i] = 0.0f;
    return z;
}
__device__ __forceinline__ ushort_t f2bf(float f) {
    __hip_bfloat16 h = __float2bfloat16(f);
    return *(ushort_t*)&h;
}
__device__ __forceinline__ float bf2f(ushort_t u) {
    union { unsigned i; float f; } v; v.i = ((unsigned)u) << 16; return v.f;
}
__device__ __forceinline__ unsigned pk2(float a, float b) {
    return (unsigned)f2bf(a) | ((unsigned)f2bf(b) << 16);
}
__device__ __forceinline__ short8 frag_from_f32(const float* __restrict__ p, float scale) {
    float4 f0 = ((const float4*)p)[0], f1 = ((const float4*)p)[1];
    frag8 r;
    r.u[0] = pk2(f0.x * scale, f0.y * scale);
    r.u[1] = pk2(f0.z * scale, f0.w * scale);
    r.u[2] = pk2(f1.x * scale, f1.y * scale);
    r.u[3] = pk2(f1.z * scale, f1.w * scale);
    return r.v;
}
__device__ __forceinline__ short8 frag_lds(const ushort_t* p) {
    frag8 r;
    r.u2[0] = *(const uint2*)p;
    r.u2[1] = *(const uint2*)(p + 4);
    return r.v;
}

// ---------------------------------------------------------------------------
// k_ax: AX[b,h,f,g] = sum_n A[n,f]*X[n,g]; A = a.a_modes (MFMA),
// X = exp(-2pi*i x.x_modes) built DIRECTLY into B-op fragments (no LDS trip).
// Wave = head. One __syncthreads total. Output: per-block partials.
// ---------------------------------------------------------------------------
__global__ __launch_bounds__(256, 4) void k_ax(
    const float* __restrict__ a, const float* __restrict__ x,
    const float* __restrict__ a_modes, const float* __restrict__ x_modes,
    float* __restrict__ AX, float* __restrict__ part, int use_part)
{
    __shared__ ushort_t s_a[256][PAD];          // a tile bf16 [pt][i]
    __shared__ float4   s_x4[256];              // x as vec4 per point
    __shared__ ushort_t s_At[NHEADS][NM][PAD];  // A^T bf16 [f][pt] (per wave)

    const int t = threadIdx.x;
    const int w = t >> 6;              // wave id == head
    const int l = t & 63;
    const int l31 = l & 31, lh = l >> 5;
    const int b  = blockIdx.x / SEGS_AX;
    const int sb = blockIdx.x % SEGS_AX;
    const int pbase = b * NPTS + sb * 256;

    // stage a (bf16) and x (vec4)
    {
        const float* arow = a + (size_t)(pbase + t) * CIN;
        unsigned* dst = (unsigned*)&s_a[t][0];
#pragma unroll
        for (int v = 0; v < 8; ++v) {
            float4 f = ((const float4*)arow)[v];
            dst[2*v]   = pk2(f.x, f.y);
            dst[2*v+1] = pk2(f.z, f.w);
        }
        for (int idx = t; idx < 256*3; idx += 256) {
            const float v = x[(size_t)pbase * 3 + idx];
            const int pt = idx / 3;
            ((float*)&s_x4[pt])[idx - 3*pt] = v;
        }
    }
    // a_modes A-op frags [m=f=l31][k=i]
    short8 amf[2];
#pragma unroll
    for (int kh = 0; kh < 2; ++kh)
        amf[kh] = frag_from_f32(a_modes + (w*NM + l31)*CIN + kh*16 + lh*8, 1.0f);
    // x_modes row for lane's g = l31
    const float xm0 = x_modes[(w*NM + l31)*3 + 0];
    const float xm1 = x_modes[(w*NM + l31)*3 + 1];
    const float xm2 = x_modes[(w*NM + l31)*3 + 2];

    floatx16 accre = zero16(), accim = zero16();
    __syncthreads();   // only block barrier

    for (int c = 0; c < 8; ++c) {
        const int p0 = c * 32;
        // ---- X frags direct: B-op [n=g=l31][k=pt], pt = p0+kh*16+lh*8+j ----
        short8 xre[2], xim[2];
#pragma unroll
        for (int kh = 0; kh < 2; ++kh) {
            frag8 re_, im_;
#pragma unroll
            for (int j = 0; j < 8; j += 2) {
                const int pl = p0 + kh*16 + lh*8 + j;
                const float4 v0 = s_x4[pl], v1 = s_x4[pl + 1];
                const float q0 = v0.x*xm0 + v0.y*xm1 + v0.z*xm2;
                const float q1 = v1.x*xm0 + v1.y*xm1 + v1.z*xm2;
                re_.u[j>>1] = pk2( __builtin_amdgcn_cosf(q0),  __builtin_amdgcn_cosf(q1));
                im_.u[j>>1] = pk2(-__builtin_amdgcn_sinf(q0), -__builtin_amdgcn_sinf(q1));
            }
            xre[kh] = re_.v; xim[kh] = im_.v;
        }
        // ---- A tile: D[f][pt] = sum_i am[f][i] * a[pt][i] ----
        floatx16 dA = zero16();
#pragma unroll
        for (int kh = 0; kh < 2; ++kh) {
            short8 af = frag_lds(&s_a[p0 + l31][kh*16 + lh*8]);  // B-op [n=pt][k=i]
            dA = MFMA32(amf[kh], af, dA, 0, 0, 0);
        }
        // transpose via wave-private LDS (in-order, no barrier)
#pragma unroll
        for (int r = 0; r < 16; ++r) {
            const int fr = (r & 3) + 8*(r >> 2) + 4*lh;
            s_At[w][fr][l31] = f2bf(dA[r]);
        }
        // ---- AX accumulate ----
#pragma unroll
        for (int kh = 0; kh < 2; ++kh) {
            short8 atf = frag_lds(&s_At[w][l31][kh*16 + lh*8]);  // A-op [f][pt]
            accre = MFMA32(atf, xre[kh], accre, 0, 0, 0);
            accim = MFMA32(atf, xim[kh], accim, 0, 0, 0);
        }
    }

    if (use_part) {
        float* pr = part + (size_t)blockIdx.x * 8192;
#pragma unroll
        for (int r = 0; r < 16; ++r) {
            const int fr = (r & 3) + 8*(r >> 2) + 4*lh;
            const int idx = (w*NM + fr)*NM + l31;
            pr[idx]        = accre[r];
            pr[idx + 4096] = accim[r];
        }
    } else {
        float* AXre = AX;
        float* AXim = AX + BATCH*NHEADS*NM*NM;
#pragma unroll
        for (int r = 0; r < 16; ++r) {
            const int fr = (r & 3) + 8*(r >> 2) + 4*lh;
            const int idx = b*4096 + (w*NM + fr)*NM + l31;
            atomicAdd(&AXre[idx], accre[r]);
            atomicAdd(&AXim[idx], accim[r]);
        }
    }
}

// ---------------------------------------------------------------------------
// k_red: AX = sum of 432 per-block partials. 512 blocks, 8-way k-split.
// ---------------------------------------------------------------------------
__global__ void k_red(const float* __restrict__ part, float* __restrict__ AX)
{
    __shared__ float s_red[8][32];
    const int t = threadIdx.x, q = t >> 5, l = t & 31;
    const int o = blockIdx.x * 32 + l;        // 0..16383
    const int bb = o >> 13, idx = o & 8191;
    float acc = 0.f;
#pragma unroll 6
    for (int sb = q; sb < SEGS_AX; sb += 8)
        acc += part[((size_t)(bb*SEGS_AX + sb))*8192 + idx];
    s_red[q][l] = acc;
    __syncthreads();
    if (t < 32) {
        float s = 0.f;
#pragma unroll
        for (int qq = 0; qq < 8; ++qq) s += s_red[qq][t];
        const int oo = blockIdx.x * 32 + t;
        const int b2 = oo >> 13, i2 = oo & 8191;
        if (i2 < 4096) AX[b2*4096 + i2] = s;
        else           AX[8192 + b2*4096 + (i2 - 4096)] = s;
    }
}

// ---------------------------------------------------------------------------
// k_w: W[b,h,o,g] = sum_f u_modes[h,f,o] * AX'[b,h,f,g]  (complex, bf16 out)
// 2 blocks x 4 waves; wave = (b,h). W layout: re[8192] then im[8192] ushort.
// ---------------------------------------------------------------------------
__global__ void k_w(const float* __restrict__ AX, const float* __restrict__ u_modes,
                    ushort_t* __restrict__ W)
{
    const int t = threadIdx.x, w = t >> 6, l = t & 63;
    const int l31 = l & 31, lh = l >> 5;
    const int pair = blockIdx.x * 4 + w;    // 0..7
    const int b = pair >> 2, h = pair & 3;
    const float* AXre = AX + b*4096 + h*1024;
    const float* AXim = AX + BATCH*4096 + b*4096 + h*1024;
    const float* um   = u_modes + h*1024;

    short8 umf[2], axr[2], axi[2];
#pragma unroll
    for (int kh = 0; kh < 2; ++kh) {
        frag8 u_, r_, i_;
#pragma unroll
        for (int j = 0; j < 8; j += 2) {
            const int f0 = kh*16 + lh*8 + j, f1 = f0 + 1;
            u_.u[j>>1] = pk2(um[f0*32 + l31], um[f1*32 + l31]);            // A-op [o][f]
            r_.u[j>>1] = pk2(AXre[f0*32 + l31]*INV_N, AXre[f1*32 + l31]*INV_N); // B-op [g][f]
            i_.u[j>>1] = pk2(AXim[f0*32 + l31]*INV_N, AXim[f1*32 + l31]*INV_N);
        }
        umf[kh] = u_.v; axr[kh] = r_.v; axi[kh] = i_.v;
    }
    floatx16 wre = zero16(), wim = zero16();
#pragma unroll
    for (int kh = 0; kh < 2; ++kh) {
        wre = MFMA32(umf[kh], axr[kh], wre, 0, 0, 0);
        wim = MFMA32(umf[kh], axi[kh], wim, 0, 0, 0);
    }
    ushort_t* Wre = W + (size_t)pair * 1024;
    ushort_t* Wim = Wre + 8192;
#pragma unroll
    for (int r = 0; r < 16; ++r) {
        const int o = (r & 3) + 8*(r >> 2) + 4*lh;
        Wre[o*32 + l31] = f2bf(wre[r]);
        Wim[o*32 + l31] = f2bf(wim[r]);
    }
}

// ---------------------------------------------------------------------------
// k_out: out = gelu( Re(Y*W) + a.fc_w^T + fc_b ); Y frags built directly.
// Wave = 32 points; one __syncthreads total.
// ---------------------------------------------------------------------------
__global__ __launch_bounds__(256, 4) void k_out(
    const float* __restrict__ a, const float* __restrict__ y,
    const float* __restrict__ y_modes, const ushort_t* __restrict__ Wg,
    const float* __restrict__ fc_w, const float* __restrict__ fc_b,
    float* __restrict__ out)
{
    __shared__ ushort_t s_Wre[NHEADS][NM][PAD];  // [h][o][g]
    __shared__ ushort_t s_Wim[NHEADS][NM][PAD];
    __shared__ float4   s_ym4[NHEADS][NM];       // y_modes vec4 per (h,g)
    __shared__ float4   s_y4[128];               // y vec4 per point
    __shared__ ushort_t s_ah[128][PAD];          // a tile bf16 [pt][i]

    const int t = threadIdx.x, w = t >> 6, l = t & 63;
    const int l31 = l & 31, lh = l >> 5;
    const int b  = blockIdx.x / SEGS_OUT;
    const int sb = blockIdx.x % SEGS_OUT;
    const int pblock = b * NPTS + sb * 128;
    const int pwave  = pblock + w * 32;

    // ---- stage ----
    {
        const unsigned* wr = (const unsigned*)Wg + b*2048;
        const unsigned* wi = (const unsigned*)(Wg + 8192) + b*2048;
        for (int idx2 = t; idx2 < 2048; idx2 += 256) {
            const int h = idx2 >> 9, o = (idx2 >> 4) & 31, g2 = (idx2 & 15) * 2;
            *(unsigned*)&s_Wre[h][o][g2] = wr[idx2];
            *(unsigned*)&s_Wim[h][o][g2] = wi[idx2];
        }
    }
    if (t < 128) {
        const int h = t >> 5, g = t & 31;
        const float* p = y_modes + (h*NM + g)*3;
        float4 v; v.x = p[0]; v.y = p[1]; v.z = p[2]; v.w = 0.f;
        s_ym4[h][g] = v;
    }
    for (int idx = t; idx < 128*3; idx += 256) {
        const float v = y[(size_t)pblock * 3 + idx];
        const int pt = idx / 3;
        ((float*)&s_y4[pt])[idx - 3*pt] = v;
    }
    if (t < 128) {
        const float* arow = a + (size_t)(pblock + t) * CIN;
        unsigned* dst = (unsigned*)&s_ah[t][0];
#pragma unroll
        for (int v = 0; v < 8; ++v) {
            float4 f = ((const float4*)arow)[v];
            dst[2*v]   = pk2(f.x, f.y);
            dst[2*v+1] = pk2(f.z, f.w);
        }
    }
    // fc_w hi/lo split frags: B-op [n=o=l31][k=i]
    short8 whi[2], wlo[2];
#pragma unroll
    for (int kh = 0; kh < 2; ++kh) {
        const float* p = fc_w + l31*CIN + kh*16 + lh*8;
        float4 f0 = ((const float4*)p)[0], f1 = ((const float4*)p)[1];
        float v[8] = {f0.x,f0.y,f0.z,f0.w,f1.x,f1.y,f1.z,f1.w};
        frag8 hi, lo;
#pragma unroll
        for (int j = 0; j < 8; ++j) {
            const ushort_t hb = f2bf(v[j]);
            hi.s[j] = hb;
            lo.s[j] = f2bf(v[j] - bf2f(hb));
        }
        whi[kh] = hi.v; wlo[kh] = lo.v;
    }
    const float fb = fc_b[l31];

    __syncthreads();   // only block barrier
    const float4 y3 = s_y4[w*32 + l31];

    // ---- skip: D[pt][o] = sum_i a[pt][i]*(whi+wlo)[o][i] ----
    floatx16 acc = zero16();
#pragma unroll
    for (int kh = 0; kh < 2; ++kh) {
        short8 af = frag_lds(&s_ah[w*32 + l31][kh*16 + lh*8]);  // A-op [m=pt][k=i]
        acc = MFMA32(af, whi[kh], acc, 0, 0, 0);
        acc = MFMA32(af, wlo[kh], acc, 0, 0, 0);
    }
    // ---- heads: acc += Yre.Wre + (-Yim).Wim ----
    for (int h = 0; h < NHEADS; ++h) {
        short8 yre[2], yim[2];
#pragma unroll
        for (int kh = 0; kh < 2; ++kh) {
            frag8 re_, im_;
#pragma unroll
            for (int j = 0; j < 8; j += 2) {
                const int g0 = kh*16 + lh*8 + j;
                const float4 m0 = s_ym4[h][g0], m1 = s_ym4[h][g0 + 1];
                const float p0 = y3.x*m0.x + y3.y*m0.y + y3.z*m0.z;
                const float p1 = y3.x*m1.x + y3.y*m1.y + y3.z*m1.z;
                re_.u[j>>1] = pk2( __builtin_amdgcn_cosf(p0),  __builtin_amdgcn_cosf(p1));
                im_.u[j>>1] = pk2(-__builtin_amdgcn_sinf(p0), -__builtin_amdgcn_sinf(p1));
            }
            yre[kh] = re_.v; yim[kh] = im_.v;
        }
#pragma unroll
        for (int kh = 0; kh < 2; ++kh) {
            short8 wrf = frag_lds(&s_Wre[h][l31][kh*16 + lh*8]);  // B-op [n=o][k=g]
            short8 wif = frag_lds(&s_Wim[h][l31][kh*16 + lh*8]);
            acc = MFMA32(yre[kh], wrf, acc, 0, 0, 0);
            acc = MFMA32(yim[kh], wif, acc, 0, 0, 0);
        }
    }
    // ---- epilogue: bias + exact GELU + store ----
#pragma unroll
    for (int r = 0; r < 16; ++r) {
        const int ptr_ = (r & 3) + 8*(r >> 2) + 4*lh;
        const float z = acc[r] + fb;
        out[(size_t)(pwave + ptr_) * COUT + l31] =
            0.5f * z * (1.0f + erff(z * 0.70710678118654752f));
    }
}

extern "C" void kernel_launch(void* const* d_in, const int* in_sizes, int n_in,
                              void* d_out, int out_size, void* d_ws, size_t ws_size,
                              hipStream_t stream) {
    (void)in_sizes; (void)n_in; (void)out_size;
    const float* a       = (const float*)d_in[0];
    const float* x       = (const float*)d_in[1];
    const float* y       = (const float*)d_in[2];
    const float* a_modes = (const float*)d_in[3];
    const float* x_modes = (const float*)d_in[4];
    const float* y_modes = (const float*)d_in[5];
    const float* u_modes = (const float*)d_in[6];
    const float* fc_w    = (const float*)d_in[7];
    const float* fc_b    = (const float*)d_in[8];
    float* out  = (float*)d_out;
    float*    AX   = (float*)d_ws;                          // 16384 f32 = 64 KB
    ushort_t* W    = (ushort_t*)((char*)d_ws + 65536);      // 16384 bf16 = 32 KB
    float*    part = (float*)((char*)d_ws + 98304);         // 864*8192 f32

    const size_t need = 98304 + (size_t)BATCH * SEGS_AX * 8192 * sizeof(float);
    const int use_part = (ws_size >= need) ? 1 : 0;

    hipMemsetAsync(AX, 0, 65536, stream);  // needed only for atomic fallback
    k_ax<<<BATCH * SEGS_AX, 256, 0, stream>>>(a, x, a_modes, x_modes, AX, part, use_part);
    if (use_part) k_red<<<512, 256, 0, stream>>>(part, AX);
    k_w<<<2, 256, 0, stream>>>(AX, u_modes, W);
    k_out<<<BATCH * SEGS_OUT, 256, 0, stream>>>(a, y, y_modes, W, fc_w, fc_b, out);
}